// Round 1
// baseline (271.015 us; speedup 1.0000x reference)
//
#include <hip/hip_runtime.h>

#define BATCH 16
#define HEADS 8
#define WORD  128
#define CELLS 16384
#define CTRL  1072      // HEADS*(WORD+6)
#define CB    256       // cells per block in read kernel

__device__ __forceinline__ float softplusf(float x) {
  return (x > 20.f) ? x : log1pf(expf(x));
}

// OP: 0 = sum, 1 = max.  scratch needs >= 16 floats; it is the big LDS buffer,
// safe to reuse because of the leading/trailing barriers.
template<int OP>
__device__ __forceinline__ float block_reduce(float v, float* scratch) {
  #pragma unroll
  for (int o = 32; o > 0; o >>= 1) {
    float u = __shfl_xor(v, o, 64);
    v = OP ? fmaxf(v, u) : (v + u);
  }
  const int t = threadIdx.x;
  __syncthreads();                       // scratch may still be in use by caller
  if ((t & 63) == 0) scratch[t >> 6] = v;
  __syncthreads();
  if (t < 64) {
    v = (t < 16) ? scratch[t] : (OP ? -3.4e38f : 0.f);
    #pragma unroll
    for (int o = 8; o > 0; o >>= 1) {
      float u = __shfl_xor(v, o, 64);
      v = OP ? fmaxf(v, u) : (v + u);
    }
    if (t == 0) scratch[0] = v;
  }
  __syncthreads();
  v = scratch[0];
  __syncthreads();                       // caller may immediately reuse scratch
  return v;
}

// ---------------- Kernel 1: cosine-similarity scores ----------------
// grid (CELLS/256, BATCH), block 256. One thread per cell.
__global__ __launch_bounds__(256)
void scores_kernel(const float* __restrict__ mem,
                   const float* __restrict__ ctrl,
                   float* __restrict__ scores) {
  const int b = blockIdx.y;
  const int c = blockIdx.x * 256 + threadIdx.x;
  const int t = threadIdx.x;

  __shared__ float kk[HEADS * WORD];   // tanh(keys), [h][w]
  __shared__ float kn[HEADS];          // ||key_h||

  for (int i = t; i < HEADS * WORD; i += 256)
    kk[i] = tanhf(ctrl[b * CTRL + i]);
  __syncthreads();
  if (t < HEADS) {
    float s = 0.f;
    for (int w = 0; w < WORD; ++w) { float v = kk[t * WORD + w]; s += v * v; }
    kn[t] = sqrtf(s);
  }
  __syncthreads();

  float dot[HEADS];
  #pragma unroll
  for (int h = 0; h < HEADS; ++h) dot[h] = 0.f;
  float nm = 0.f;

  const float4* mrow = (const float4*)&mem[((size_t)b * CELLS + c) * WORD];
  const float4* k4   = (const float4*)kk;
  for (int w4 = 0; w4 < WORD / 4; ++w4) {
    float4 m = mrow[w4];
    nm = fmaf(m.x, m.x, fmaf(m.y, m.y, fmaf(m.z, m.z, fmaf(m.w, m.w, nm))));
    #pragma unroll
    for (int h = 0; h < HEADS; ++h) {
      float4 k = k4[h * (WORD / 4) + w4];   // uniform -> LDS broadcast
      dot[h] = fmaf(m.x, k.x, fmaf(m.y, k.y, fmaf(m.z, k.z, fmaf(m.w, k.w, dot[h]))));
    }
  }
  nm = sqrtf(nm);
  #pragma unroll
  for (int h = 0; h < HEADS; ++h)
    scores[((size_t)(b * HEADS + h)) * CELLS + c] = dot[h] / (kn[h] * nm + 1e-8f);
}

// ---------------- Kernel 2: softmax / interp / shift / sharpen ----------------
// grid (BATCH*HEADS), block 1024, 64 KB LDS (exactly).
__global__ __launch_bounds__(1024)
void weights_kernel(const float* __restrict__ scores,
                    const float* __restrict__ ctrl,
                    const float* __restrict__ bias,
                    float* __restrict__ rd) {
  const int bh = blockIdx.x;
  const int b = bh >> 3, h = bh & 7;
  const int t = threadIdx.x;

  __shared__ float buf[CELLS];   // 64 KB: reduction scratch, then w_interp row

  const float* cb = ctrl + b * CTRL;
  const float beta  = softplusf(cb[1024 + h]);
  const float gate  = 1.f / (1.f + expf(-cb[1032 + h]));
  float s0 = cb[1040 + h * 3 + 0];
  float s1 = cb[1040 + h * 3 + 1];
  float s2 = cb[1040 + h * 3 + 2];
  {
    float sm = fmaxf(s0, fmaxf(s1, s2));
    float e0 = expf(s0 - sm), e1 = expf(s1 - sm), e2 = expf(s2 - sm);
    float inv = 1.f / (e0 + e1 + e2);
    s0 = e0 * inv; s1 = e1 * inv; s2 = e2 * inv;
  }
  const float gamma = 1.f + softplusf(cb[1064 + h]);

  // --- content softmax: x = scores*beta ---
  float x[16];
  const float* srow = scores + (size_t)bh * CELLS;
  #pragma unroll
  for (int i = 0; i < 16; ++i) x[i] = srow[t + i * 1024] * beta;
  float mx = x[0];
  #pragma unroll
  for (int i = 1; i < 16; ++i) mx = fmaxf(mx, x[i]);
  mx = block_reduce<1>(mx, buf);
  float se = 0.f;
  #pragma unroll
  for (int i = 0; i < 16; ++i) { x[i] = expf(x[i] - mx); se += x[i]; }
  se = block_reduce<0>(se, buf);

  // --- prev-weights softmax of bias row (same for all b) ---
  float y[16];
  const float* brow = bias + (size_t)h * CELLS;
  #pragma unroll
  for (int i = 0; i < 16; ++i) y[i] = brow[t + i * 1024];
  float mb = y[0];
  #pragma unroll
  for (int i = 1; i < 16; ++i) mb = fmaxf(mb, y[i]);
  mb = block_reduce<1>(mb, buf);
  float sb = 0.f;
  #pragma unroll
  for (int i = 0; i < 16; ++i) { y[i] = expf(y[i] - mb); sb += y[i]; }
  sb = block_reduce<0>(sb, buf);

  // --- interpolate into LDS ---
  const float a1 = gate / se;
  const float a2 = (1.f - gate) / sb;
  #pragma unroll
  for (int i = 0; i < 16; ++i)
    buf[t + i * 1024] = a1 * x[i] + a2 * y[i];
  __syncthreads();

  // --- circular shift + sharpen ---
  float sh[16]; float ss = 0.f;
  #pragma unroll
  for (int i = 0; i < 16; ++i) {
    int c = t + i * 1024;
    float wm = buf[(c + CELLS - 1) & (CELLS - 1)];
    float w0 = buf[c];
    float wp = buf[(c + 1) & (CELLS - 1)];
    float ws = fmaf(s0, wm, fmaf(s1, w0, s2 * wp));
    float p = powf(ws, gamma);
    sh[i] = p; ss += p;
  }
  // block_reduce has a leading barrier, so neighbor reads are done before reuse
  ss = block_reduce<0>(ss, buf);
  const float inv = 1.f / (ss + 1e-8f);
  float* rrow = rd + (size_t)bh * CELLS;
  #pragma unroll
  for (int i = 0; i < 16; ++i) rrow[t + i * 1024] = sh[i] * inv;
}

// ---------------- Kernel 3: weighted read ----------------
// grid (CELLS/CB, BATCH), block 256.
__global__ __launch_bounds__(256)
void read_kernel(const float* __restrict__ mem,
                 const float* __restrict__ rd,
                 float* __restrict__ out) {
  const int b  = blockIdx.y;
  const int c0 = blockIdx.x * CB;
  const int t  = threadIdx.x;

  __shared__ float rds[HEADS][CB];           // 8 KB
  __shared__ float red[8][HEADS * WORD];     // 32 KB, [cc][h*128+w]

  for (int i = t; i < HEADS * CB; i += 256)
    rds[i >> 8][i & 255] = rd[((size_t)b * HEADS + (i >> 8)) * CELLS + c0 + (i & 255)];
  __syncthreads();

  const int w4 = (t & 31) * 4;   // word offset (float4)
  const int cc = t >> 5;         // 8-way split over cells
  float4 acc[HEADS];
  #pragma unroll
  for (int h = 0; h < HEADS; ++h) acc[h] = make_float4(0.f, 0.f, 0.f, 0.f);

  for (int c = cc; c < CB; c += 8) {
    float4 m = *(const float4*)&mem[((size_t)b * CELLS + c0 + c) * WORD + w4];
    #pragma unroll
    for (int h = 0; h < HEADS; ++h) {
      float r = rds[h][c];                   // 2 addrs/wave -> broadcast
      acc[h].x = fmaf(r, m.x, acc[h].x);
      acc[h].y = fmaf(r, m.y, acc[h].y);
      acc[h].z = fmaf(r, m.z, acc[h].z);
      acc[h].w = fmaf(r, m.w, acc[h].w);
    }
  }

  #pragma unroll
  for (int h = 0; h < HEADS; ++h)
    *(float4*)&red[cc][h * WORD + w4] = acc[h];
  __syncthreads();

  // 1024 outputs, 256 threads -> one float4 each, summed over cc
  float4 s = *(float4*)&red[0][t * 4];
  #pragma unroll
  for (int c2 = 1; c2 < 8; ++c2) {
    float4 v = *(float4*)&red[c2][t * 4];
    s.x += v.x; s.y += v.y; s.z += v.z; s.w += v.w;
  }
  const int h = t >> 5;            // (t*4)/128
  const int w = (t * 4) & 127;
  float* o = &out[((size_t)b * HEADS + h) * WORD + w];
  atomicAdd(o + 0, s.x);
  atomicAdd(o + 1, s.y);
  atomicAdd(o + 2, s.z);
  atomicAdd(o + 3, s.w);
}

extern "C" void kernel_launch(void* const* d_in, const int* in_sizes, int n_in,
                              void* d_out, int out_size, void* d_ws, size_t ws_size,
                              hipStream_t stream) {
  const float* mem  = (const float*)d_in[0];
  const float* ctrl = (const float*)d_in[1];
  const float* bias = (const float*)d_in[2];
  float* out    = (float*)d_out;
  float* scores = (float*)d_ws;                              // 8 MB
  float* rd     = scores + (size_t)BATCH * HEADS * CELLS;    // 8 MB (needs 16 MB ws)

  hipMemsetAsync(d_out, 0, sizeof(float) * BATCH * HEADS * WORD, stream);

  scores_kernel<<<dim3(CELLS / 256, BATCH), 256, 0, stream>>>(mem, ctrl, scores);
  weights_kernel<<<dim3(BATCH * HEADS), 1024, 0, stream>>>(scores, ctrl, bias, rd);
  read_kernel<<<dim3(CELLS / CB, BATCH), 256, 0, stream>>>(mem, rd, out);
}